// Round 4
// baseline (415.806 us; speedup 1.0000x reference)
//
#include <hip/hip_runtime.h>
#include <stdint.h>

#define BB 4
#define CC 256
#define HH 64
#define WWD 64
#define NN 4096
#define LOG2E 1.4426950408889634f

typedef __attribute__((ext_vector_type(8))) short short8;
typedef __attribute__((ext_vector_type(4))) float f32x4;
typedef __attribute__((ext_vector_type(16))) float f32x16;
typedef __attribute__((ext_vector_type(4))) unsigned short us4;

__device__ __forceinline__ unsigned short f2bf(float f) {
  unsigned int u = __float_as_uint(f);
  u += 0x7fffu + ((u >> 16) & 1u);          // RNE
  return (unsigned short)(u >> 16);
}
__device__ __forceinline__ float bf2f(unsigned short h) {
  return __uint_as_float(((unsigned int)h) << 16);
}
__device__ __forceinline__ short8 ld8(const unsigned short* p) {
  return *reinterpret_cast<const short8*>(p);
}
__device__ __forceinline__ int rowmap(int reg, int h) {   // 32x32 C/D row map
  return (reg & 3) + 8 * (reg >> 2) + 4 * h;
}
// fragment-linear element offset for value (n,o) in a [4096n x 256o] frag tensor
__device__ __forceinline__ size_t fragoff(int b, int n, int o) {
  return (((size_t)b * 128 + (n >> 5)) * 16 + (o >> 4)) * 512 +
         (size_t)(((n & 31) + 32 * ((o >> 3) & 1)) * 8 + (o & 7));
}

// ---------------------------------------------------------------- weights cast
__global__ void k_cast_w(const float* __restrict__ qw, const float* __restrict__ kvw,
                         const float* __restrict__ ow, unsigned short* __restrict__ Wb) {
  int i = blockIdx.x * 256 + threadIdx.x;   // 262144 total
  float v;
  if (i < 65536) v = qw[i];
  else if (i < 196608) v = kvw[i - 65536];
  else v = ow[i - 196608];
  Wb[i] = f2bf(v);
}

// ------------------------------------ transpose x -> Xt(B,N,C) bf16 (+ channel sums)
__global__ void k_transpose(const float* __restrict__ xs, const float* __restrict__ xo,
                            unsigned short* __restrict__ XtS, unsigned short* __restrict__ XtO,
                            float* __restrict__ psum) {
  __shared__ float tb[64][65];
  __shared__ float rb[4][64];
  int n0 = blockIdx.x * 64, c0 = blockIdx.y * 64;
  int z = blockIdx.z, b = z >> 1, which = z & 1;
  const float* src = which ? xo : xs;
  unsigned short* dst = which ? XtO : XtS;
  int tid = threadIdx.x;
  int nl = tid & 63, cl4 = tid >> 6;
  for (int p = 0; p < 16; ++p) {
    int cl = p * 4 + cl4;
    tb[cl][nl] = src[((size_t)(b * CC + c0 + cl)) * NN + n0 + nl];
  }
  __syncthreads();
  // vectorized store: thread -> 4 n x 4 c
  int cb = (tid & 15) * 4;
#pragma unroll
  for (int i = 0; i < 4; ++i) {
    int nloc = i * 16 + (tid >> 4);
    us4 r;
#pragma unroll
    for (int j = 0; j < 4; ++j) r[j] = f2bf(tb[cb + j][nloc]);
    *reinterpret_cast<us4*>(&dst[((size_t)b * NN + n0 + nloc) * CC + c0 + cb]) = r;
  }
  if (which == 0) {                 // block-uniform branch: channel sums
    int c = tid & 63, ni = tid >> 6;
    float s = 0.f;
    for (int i = 0; i < 16; ++i) s += tb[c][i * 4 + ni];
    rb[ni][c] = s;
    __syncthreads();
    if (tid < 64) {
      float t = rb[0][tid] + rb[1][tid] + rb[2][tid] + rb[3][tid];
      atomicAdd(&psum[b * CC + c0 + tid], t);
    }
  }
}

// ---------------------------------------------------------------- gate (SE path)
__global__ void k_gate(const float* __restrict__ psum, const float* __restrict__ g1w,
                       const float* __restrict__ g1b, const float* __restrict__ g2w,
                       const float* __restrict__ g2b, float* __restrict__ gate) {
  __shared__ float hp[64][5];
  int b = blockIdx.x;
  int tid = threadIdx.x;
  int j = tid >> 2, cq = tid & 3;
  float s = 0.f;
  for (int c = cq * 64; c < cq * 64 + 64; ++c)
    s = fmaf(psum[b * CC + c] * (1.f / 4096.f), g1w[j * CC + c], s);
  hp[j][cq] = s;
  __syncthreads();
  if (tid < 64) {
    float hh = fmaxf(hp[tid][0] + hp[tid][1] + hp[tid][2] + hp[tid][3] + g1b[tid], 0.f);
    float t = hh * g2w[tid];
    for (int off = 32; off; off >>= 1) t += __shfl_down(t, off, 64);
    if (tid == 0) gate[b] = 1.f / (1.f + expf(-(t + g2b[0])));
  }
}

// ---------------------------- depthwise 3x3 + BN + SiLU -> localT (B,N,C) bf16
__global__ void k_dwconv(const float* __restrict__ x, const float* __restrict__ dww,
                         const float* __restrict__ dwb, const float* __restrict__ bng,
                         const float* __restrict__ bnb, const float* __restrict__ bnm,
                         const float* __restrict__ bnv, unsigned short* __restrict__ localT) {
  __shared__ float lb[64][65];
  int c0 = blockIdx.x * 64, h = blockIdx.y, b = blockIdx.z;
  int tid = threadIdx.x;
  int w = tid & 63, cl4 = tid >> 6;
  for (int p = 0; p < 16; ++p) {
    int cl = p * 4 + cl4, c = c0 + cl;
    float acc = 0.f;
#pragma unroll
    for (int di = -1; di <= 1; ++di) {
      int hh = h + di;
      if (hh < 0 || hh >= HH) continue;
#pragma unroll
      for (int dj = -1; dj <= 1; ++dj) {
        int ww = w + dj;
        if (ww < 0 || ww >= WWD) continue;
        acc += x[(((size_t)(b * CC + c)) * HH + hh) * WWD + ww] * dww[c * 9 + (di + 1) * 3 + (dj + 1)];
      }
    }
    float y = acc + dwb[c];
    float sc = bng[c] * rsqrtf(bnv[c] + 1e-5f);
    float v = (y - bnm[c]) * sc + bnb[c];
    float sg = 1.f / (1.f + __expf(-v));
    lb[cl][w] = v * sg;
  }
  __syncthreads();
  int cb = (tid & 15) * 4;
#pragma unroll
  for (int i = 0; i < 4; ++i) {
    int wl = i * 16 + (tid >> 4);
    us4 r;
#pragma unroll
    for (int j = 0; j < 4; ++j) r[j] = f2bf(lb[cb + j][wl]);
    *reinterpret_cast<us4*>(&localT[((size_t)b * NN + h * WWD + wl) * CC + c0 + cb]) = r;
  }
}

// --------- fused Q,K,V projections. id 0/1: Q,K in FRAGMENT-LINEAR layout (flash reads
// coalesced frags straight from global). id 2: V row-major [o][n] for LDS staging in flash.
__global__ __launch_bounds__(256, 4) void k_qkv(
    const unsigned short* __restrict__ XtS, const unsigned short* __restrict__ XtO,
    const unsigned short* __restrict__ Wb, const float* __restrict__ qb,
    const float* __restrict__ kvb, unsigned short* __restrict__ Qt,
    unsigned short* __restrict__ Kt, unsigned short* __restrict__ Vv) {
  __shared__ unsigned short Xs[64][264];   // stride 528B == 16 mod 128: conflict-free b128
  int n0 = blockIdx.x * 64, id = blockIdx.y, b = blockIdx.z;
  const unsigned short* Xt = (id == 0) ? XtS : XtO;
  const unsigned short* W = Wb + id * 65536;
  int tid = threadIdx.x, wave = tid >> 6, lane = tid & 63, l31 = lane & 31, h = lane >> 5;
#pragma unroll
  for (int p = 0; p < 8; ++p) {
    int r = p * 8 + (tid >> 5), c = (tid & 31) * 8;
    *reinterpret_cast<uint4*>(&Xs[r][c]) =
        *reinterpret_cast<const uint4*>(Xt + ((size_t)b * NN + n0 + r) * CC + c);
  }
  __syncthreads();
  int o0 = wave * 64;
  f32x16 acc[4] = {};
  if (id < 2) {
#pragma unroll
    for (int t = 0; t < 16; ++t) {
      short8 a0 = ld8(&Xs[l31][t * 16 + h * 8]);
      short8 a1 = ld8(&Xs[32 + l31][t * 16 + h * 8]);
      short8 b0 = ld8(W + (size_t)(o0 + l31) * CC + t * 16 + h * 8);
      short8 b1 = ld8(W + (size_t)(o0 + 32 + l31) * CC + t * 16 + h * 8);
      acc[0] = __builtin_amdgcn_mfma_f32_32x32x16_bf16(a0, b0, acc[0], 0, 0, 0);
      acc[1] = __builtin_amdgcn_mfma_f32_32x32x16_bf16(a0, b1, acc[1], 0, 0, 0);
      acc[2] = __builtin_amdgcn_mfma_f32_32x32x16_bf16(a1, b0, acc[2], 0, 0, 0);
      acc[3] = __builtin_amdgcn_mfma_f32_32x32x16_bf16(a1, b1, acc[3], 0, 0, 0);
    }
    const float* bias = id ? kvb : qb;
    unsigned short* Out = id ? Kt : Qt;
    float scale = id ? 1.0f : 0.0625f;
#pragma unroll
    for (int nt = 0; nt < 2; ++nt)
#pragma unroll
      for (int ot = 0; ot < 2; ++ot) {
        int o = o0 + ot * 32 + l31;
        float bv = bias[o];
#pragma unroll
        for (int reg = 0; reg < 16; ++reg) {
          int n = n0 + nt * 32 + rowmap(reg, h);
          Out[fragoff(b, n, o)] = f2bf((acc[nt * 2 + ot][reg] + bv) * scale);
        }
      }
  } else {
    // V[o][n]: A = W rows (L2), B = Xt rows (LDS)
#pragma unroll
    for (int t = 0; t < 16; ++t) {
      short8 a0 = ld8(W + (size_t)(o0 + l31) * CC + t * 16 + h * 8);
      short8 a1 = ld8(W + (size_t)(o0 + 32 + l31) * CC + t * 16 + h * 8);
      short8 b0 = ld8(&Xs[l31][t * 16 + h * 8]);
      short8 b1 = ld8(&Xs[32 + l31][t * 16 + h * 8]);
      acc[0] = __builtin_amdgcn_mfma_f32_32x32x16_bf16(a0, b0, acc[0], 0, 0, 0);
      acc[1] = __builtin_amdgcn_mfma_f32_32x32x16_bf16(a0, b1, acc[1], 0, 0, 0);
      acc[2] = __builtin_amdgcn_mfma_f32_32x32x16_bf16(a1, b0, acc[2], 0, 0, 0);
      acc[3] = __builtin_amdgcn_mfma_f32_32x32x16_bf16(a1, b1, acc[3], 0, 0, 0);
    }
#pragma unroll
    for (int ot = 0; ot < 2; ++ot)
#pragma unroll
      for (int nt = 0; nt < 2; ++nt)
#pragma unroll
        for (int reg = 0; reg < 16; ++reg) {
          int o = o0 + ot * 32 + rowmap(reg, h);
          int n = n0 + nt * 32 + l31;
          Vv[((size_t)b * CC + o) * NN + n] = f2bf(acc[ot * 2 + nt][reg] + kvb[CC + o]);
        }
  }
}

// --------- out projection: out[o][n] = sum_c W[o][c] * fusedT[n][c] + ob  (f32 out)
__global__ __launch_bounds__(256, 4) void k_out(
    const unsigned short* __restrict__ W, const float* __restrict__ ob,
    const unsigned short* __restrict__ fusedT, float* __restrict__ out) {
  __shared__ unsigned short Xs[64][264];
  int n0 = blockIdx.x * 64, o0 = blockIdx.y * 128, b = blockIdx.z;
  int tid = threadIdx.x, wave = tid >> 6, lane = tid & 63, l31 = lane & 31, h = lane >> 5;
#pragma unroll
  for (int p = 0; p < 8; ++p) {
    int r = p * 8 + (tid >> 5), c = (tid & 31) * 8;
    *reinterpret_cast<uint4*>(&Xs[r][c]) =
        *reinterpret_cast<const uint4*>(fusedT + ((size_t)b * NN + n0 + r) * CC + c);
  }
  int obase = o0 + wave * 32;
  short8 af[16];
#pragma unroll
  for (int t = 0; t < 16; ++t) af[t] = ld8(W + (size_t)(obase + l31) * CC + t * 16 + h * 8);
  __syncthreads();
  f32x16 acc[2] = {};
#pragma unroll
  for (int t = 0; t < 16; ++t) {
    short8 b0 = ld8(&Xs[l31][t * 16 + h * 8]);
    short8 b1 = ld8(&Xs[32 + l31][t * 16 + h * 8]);
    acc[0] = __builtin_amdgcn_mfma_f32_32x32x16_bf16(af[t], b0, acc[0], 0, 0, 0);
    acc[1] = __builtin_amdgcn_mfma_f32_32x32x16_bf16(af[t], b1, acc[1], 0, 0, 0);
  }
#pragma unroll
  for (int nt = 0; nt < 2; ++nt)
#pragma unroll
    for (int reg = 0; reg < 16; ++reg) {
      int o = obase + rowmap(reg, h);
      int n = n0 + nt * 32 + l31;
      out[((size_t)b * CC + o) * NN + n] = acc[nt][reg] + ob[o];
    }
}

// ------------- flash attention v3: K frags direct from global (frag-linear), V via LDS.
// LDS ~46.6 KB -> 3 blocks/CU. V staging overlaps QK MFMAs (2 barriers/iter).
__global__ __launch_bounds__(256, 3) void k_flash3(
    const unsigned short* __restrict__ Qt, const unsigned short* __restrict__ Kt,
    const unsigned short* __restrict__ V, const unsigned short* __restrict__ localT,
    const float* __restrict__ gate, float* __restrict__ Opart, float* __restrict__ Lpart,
    unsigned short* __restrict__ fusedT) {
  __shared__ unsigned short Vs[256][72];   // stride 144B == 16 mod 128
  __shared__ unsigned short Ps[64][72];
  __shared__ float lred[2][64];
  __shared__ float ltot[64];
  int n0 = blockIdx.x * 64, b = blockIdx.y, sp = blockIdx.z, nsp = gridDim.z;
  int tid = threadIdx.x, wave = tid >> 6, lane = tid & 63, l31 = lane & 31, h = lane >> 5;
  int rw = wave & 1, cw = wave >> 1;
  // Q fragments (frag-linear, coalesced 1KB loads), rows rw*32.. for whole sweep
  const unsigned short* qbase = Qt + (((size_t)b * 128 + (n0 >> 5) + rw) * 16) * 512 + lane * 8;
  short8 qf[16];
#pragma unroll
  for (int t = 0; t < 16; ++t) qf[t] = ld8(qbase + t * 512);
  f32x16 O[4] = {};
  float lacc[16] = {};
  int m_lo = (64 * sp) / nsp, m_hi = (64 * (sp + 1)) / nsp;
  for (int mt = m_lo; mt < m_hi; ++mt) {
    int m0 = mt * 64;
    __syncthreads();          // prior iter's Vs/Ps reads complete
    // stage V tile (256c x 64m) — overlaps with S-phase MFMAs below
#pragma unroll
    for (int p = 0; p < 8; ++p) {
      int ccol = p * 32 + (tid >> 3), mm = (tid & 7) * 8;
      *reinterpret_cast<uint4*>(&Vs[ccol][mm]) =
          *reinterpret_cast<const uint4*>(V + ((size_t)b * CC + ccol) * NN + m0 + mm);
    }
    // S = Q K^T for this wave's 32x32 tile; K frags straight from global (coalesced)
    const unsigned short* kbase =
        Kt + (((size_t)b * 128 + mt * 2 + cw) * 16) * 512 + lane * 8;
    f32x16 S = {};
#pragma unroll
    for (int t = 0; t < 16; ++t) {
      short8 kf = ld8(kbase + t * 512);
      S = __builtin_amdgcn_mfma_f32_32x32x16_bf16(qf[t], kf, S, 0, 0, 0);
    }
    // P = exp(S); row-sum accumulate; write P to LDS
#pragma unroll
    for (int reg = 0; reg < 16; ++reg) {
      float p = __builtin_exp2f(S[reg] * LOG2E);
      lacc[reg] += p;
      Ps[rw * 32 + rowmap(reg, h)][cw * 32 + l31] = f2bf(p);
    }
    __syncthreads();          // Vs staged + Ps visible
    // O += P * V^T : rows rw*32, cols cw*128, k = 64
#pragma unroll
    for (int t = 0; t < 4; ++t) {
      short8 pf = ld8(&Ps[rw * 32 + l31][t * 16 + h * 8]);
#pragma unroll
      for (int ct = 0; ct < 4; ++ct) {
        short8 vf = ld8(&Vs[cw * 128 + ct * 32 + l31][t * 16 + h * 8]);
        O[ct] = __builtin_amdgcn_mfma_f32_32x32x16_bf16(pf, vf, O[ct], 0, 0, 0);
      }
    }
  }
  // row-sum reduction over this wave's 32 cols
#pragma unroll
  for (int reg = 0; reg < 16; ++reg) {
    float v = lacc[reg];
#pragma unroll
    for (int msk = 1; msk < 32; msk <<= 1) v += __shfl_xor(v, msk, 64);
    lacc[reg] = v;
  }
  __syncthreads();
#pragma unroll
  for (int g = 0; g < 16; ++g)
    if (l31 == g) lred[cw][rw * 32 + rowmap(g, h)] = lacc[g];
  __syncthreads();
  size_t obase2 = (size_t)(b * nsp + sp) * NN;
  if (nsp == 1) {
    if (tid < 64) ltot[tid] = lred[0][tid] + lred[1][tid];
    __syncthreads();
    float gv = gate[b];
    float inv[16];
#pragma unroll
    for (int reg = 0; reg < 16; ++reg)
      inv[reg] = gv / ltot[rw * 32 + rowmap(reg, h)];
#pragma unroll
    for (int ct = 0; ct < 4; ++ct)
#pragma unroll
      for (int reg = 0; reg < 16; ++reg) {
        int n = n0 + rw * 32 + rowmap(reg, h);
        int c = cw * 128 + ct * 32 + l31;
        size_t idx = ((size_t)b * NN + n) * CC + c;
        fusedT[idx] = f2bf(bf2f(localT[idx]) + O[ct][reg] * inv[reg]);
      }
  } else {
    if (tid < 64) Lpart[obase2 + n0 + tid] = lred[0][tid] + lred[1][tid];
#pragma unroll
    for (int ct = 0; ct < 4; ++ct)
#pragma unroll
      for (int reg = 0; reg < 16; ++reg) {
        int n = n0 + rw * 32 + rowmap(reg, h);
        int c = cw * 128 + ct * 32 + l31;
        Opart[(obase2 + n) * CC + c] = O[ct][reg];
      }
  }
}

// ------------- combine split partials: fusedT = localT + gate * (sum O_sp)/(sum l_sp)
__global__ void k_combine(const float* __restrict__ Opart, const float* __restrict__ Lpart,
                          const unsigned short* __restrict__ localT, const float* __restrict__ gate,
                          unsigned short* __restrict__ fusedT, int nsplit) {
  int b = blockIdx.y, tid = threadIdx.x;
  int n = blockIdx.x * 4 + (tid >> 6);
  int c = (tid & 63) * 4;
  float lsum = 0.f;
  for (int sp = 0; sp < nsplit; ++sp) lsum += Lpart[(size_t)(b * nsplit + sp) * NN + n];
  float g = gate[b] / lsum;
  f32x4 o = {};
  for (int sp = 0; sp < nsplit; ++sp)
    o += *reinterpret_cast<const f32x4*>(
        &Opart[((size_t)(b * nsplit + sp) * NN + n) * CC + c]);
  size_t base = ((size_t)b * NN + n) * CC + c;
  us4 lv = *reinterpret_cast<const us4*>(localT + base);
  us4 r;
#pragma unroll
  for (int j = 0; j < 4; ++j) r[j] = f2bf(bf2f(lv[j]) + o[j] * g);
  *reinterpret_cast<us4*>(fusedT + base) = r;
}

// ---------------------------------------------------------------------------- launch
extern "C" void kernel_launch(void* const* d_in, const int* in_sizes, int n_in,
                              void* d_out, int out_size, void* d_ws, size_t ws_size,
                              hipStream_t stream) {
  const float* xs  = (const float*)d_in[0];
  const float* xo  = (const float*)d_in[1];
  const float* qw  = (const float*)d_in[2];
  const float* qb  = (const float*)d_in[3];
  const float* kvw = (const float*)d_in[4];
  const float* kvb = (const float*)d_in[5];
  const float* g1w = (const float*)d_in[6];
  const float* g1b = (const float*)d_in[7];
  const float* g2w = (const float*)d_in[8];
  const float* g2b = (const float*)d_in[9];
  const float* dww = (const float*)d_in[10];
  const float* dwb = (const float*)d_in[11];
  const float* bng = (const float*)d_in[12];
  const float* bnb = (const float*)d_in[13];
  const float* bnm = (const float*)d_in[14];
  const float* bnv = (const float*)d_in[15];
  const float* ow  = (const float*)d_in[16];
  const float* ob  = (const float*)d_in[17];
  float* out = (float*)d_out;
  char* ws = (char*)d_ws;

  const size_t SZ = (size_t)BB * NN * CC * 2;             // 8 MB per bf16 tensor
  unsigned short* XtS = (unsigned short*)(ws);            // -> fusedT later
  unsigned short* XtO = (unsigned short*)(ws + SZ);       // -> localT later
  unsigned short* Qt  = (unsigned short*)(ws + 2 * SZ);   // fragment-linear
  unsigned short* Kt  = (unsigned short*)(ws + 3 * SZ);   // fragment-linear
  unsigned short* Vv  = (unsigned short*)(ws + 4 * SZ);   // row-major [b][o][n]
  unsigned short* Wb  = (unsigned short*)(ws + 5 * SZ);   // 512 KB
  float* psum = (float*)(ws + 5 * SZ + 524288);           // 4 KB
  float* gate = (float*)(ws + 5 * SZ + 524288 + 4096);    // small
  size_t tail = 5 * SZ + 524288 + 8192;
  float* Lpart = (float*)(ws + tail);                     // up to 256 KB
  float* Opart = (float*)(ws + tail + 262144);            // S*16 MB
  unsigned short* localT = XtO;   // written by k_dwconv AFTER k_qkv reads XtO
  unsigned short* fusedT = XtS;   // written after k_qkv reads XtS

  size_t fixed = tail + 262144;
  int S = 1;
  if (ws_size >= fixed + 3ull * 16777216) S = 3;          // 768 blocks = 3/CU
  else if (ws_size >= fixed + 2ull * 16777216) S = 2;

  hipMemsetAsync(psum, 0, BB * CC * sizeof(float), stream);
  k_cast_w<<<1024, 256, 0, stream>>>(qw, kvw, ow, Wb);
  k_transpose<<<dim3(64, 4, 8), 256, 0, stream>>>(xs, xo, XtS, XtO, psum);
  k_gate<<<4, 256, 0, stream>>>(psum, g1w, g1b, g2w, g2b, gate);
  k_qkv<<<dim3(64, 3, 4), 256, 0, stream>>>(XtS, XtO, Wb, qb, kvb, Qt, Kt, Vv);
  k_dwconv<<<dim3(4, 64, 4), 256, 0, stream>>>(xs, dww, dwb, bng, bnb, bnm, bnv, localT);
  k_flash3<<<dim3(64, 4, S), 256, 0, stream>>>(Qt, Kt, Vv, localT, gate, Opart, Lpart,
                                               fusedT);
  if (S > 1)
    k_combine<<<dim3(1024, 4), 256, 0, stream>>>(Opart, Lpart, localT, gate, fusedT, S);
  k_out<<<dim3(64, 2, 4), 256, 0, stream>>>(Wb + 196608, ob, fusedT, out);
}

// Round 5
// 282.835 us; speedup vs baseline: 1.4701x; 1.4701x over previous
//
#include <hip/hip_runtime.h>
#include <stdint.h>

#define BB 4
#define CC 256
#define HH 64
#define WWD 64
#define NN 4096
#define LOG2E 1.4426950408889634f

typedef __attribute__((ext_vector_type(8))) short short8;
typedef __attribute__((ext_vector_type(4))) float f32x4;
typedef __attribute__((ext_vector_type(16))) float f32x16;
typedef __attribute__((ext_vector_type(4))) unsigned short us4;

__device__ __forceinline__ unsigned short f2bf(float f) {
  unsigned int u = __float_as_uint(f);
  u += 0x7fffu + ((u >> 16) & 1u);          // RNE
  return (unsigned short)(u >> 16);
}
__device__ __forceinline__ float bf2f(unsigned short h) {
  return __uint_as_float(((unsigned int)h) << 16);
}
__device__ __forceinline__ short8 ld8(const unsigned short* p) {
  return *reinterpret_cast<const short8*>(p);
}
__device__ __forceinline__ int rowmap(int reg, int h) {   // 32x32 C/D row map
  return (reg & 3) + 8 * (reg >> 2) + 4 * h;
}

// ---------------- k_pre: z<8 -> transpose (+psum partials, +dwconv for x_self);
//                  z==8 -> weight fp32->bf16 cast slice
__global__ __launch_bounds__(256, 2) void k_pre(
    const float* __restrict__ xs, const float* __restrict__ xo,
    const float* __restrict__ dww, const float* __restrict__ dwb,
    const float* __restrict__ bng, const float* __restrict__ bnb,
    const float* __restrict__ bnm, const float* __restrict__ bnv,
    const float* __restrict__ qw, const float* __restrict__ kvw,
    const float* __restrict__ ow, unsigned short* __restrict__ XtS,
    unsigned short* __restrict__ XtO, unsigned short* __restrict__ localT,
    float* __restrict__ psumA, unsigned short* __restrict__ Wb) {
  __shared__ float rb3[3][64][67];          // stride 67 f32: 2-way LDS aliasing only
  __shared__ unsigned short sb[64][67];
  int tid = threadIdx.x;
  if (blockIdx.z == 8) {                    // weight cast: 256 blocks x 1024 elems
    int i = (blockIdx.x * 64 + blockIdx.y) * 1024 + tid * 4;
    const float* src;
    if (i < 65536) src = qw + i;
    else if (i < 196608) src = kvw + (i - 65536);
    else src = ow + (i - 196608);
    f32x4 v = *reinterpret_cast<const f32x4*>(src);
    us4 r;
#pragma unroll
    for (int j = 0; j < 4; ++j) r[j] = f2bf(v[j]);
    *reinterpret_cast<us4*>(Wb + i) = r;
    return;
  }
  int c0 = blockIdx.x * 64, h = blockIdx.y;
  int b = blockIdx.z >> 1, which = blockIdx.z & 1;
  const float* src = which ? xo : xs;
  int wq = tid >> 6, w = tid & 63;
  int dlo = which ? 1 : 0, dhi = which ? 1 : 2;
  for (int d = dlo; d <= dhi; ++d) {
    int hh = h + d - 1;
    bool ok = (hh >= 0 && hh < HH);
    for (int p = 0; p < 16; ++p) {
      int cl = p * 4 + wq;
      rb3[d][cl][w + 1] =
          ok ? src[(((size_t)(b * CC + c0 + cl)) * HH + hh) * WWD + w] : 0.f;
    }
    if (tid < 64) { rb3[d][tid][0] = 0.f; rb3[d][tid][65] = 0.f; }
  }
  __syncthreads();
  // transpose-store middle row -> Xt
  unsigned short* dst = which ? XtO : XtS;
  int n0 = h * 64, cb = (tid & 15) * 4;
#pragma unroll
  for (int i = 0; i < 4; ++i) {
    int wl = i * 16 + (tid >> 4);
    us4 r;
#pragma unroll
    for (int j = 0; j < 4; ++j) r[j] = f2bf(rb3[1][cb + j][wl + 1]);
    *reinterpret_cast<us4*>(&dst[((size_t)b * NN + n0 + wl) * CC + c0 + cb]) = r;
  }
  if (which) return;
  // channel-sum partial for this (b, h)
  if (tid < 64) {
    float s = 0.f;
    for (int ww = 0; ww < 64; ++ww) s += rb3[1][tid][ww + 1];
    psumA[((size_t)(b * 64 + h)) * CC + c0 + tid] = s;
  }
  // depthwise 3x3 + BN + SiLU
  for (int p = 0; p < 16; ++p) {
    int cl = p * 4 + wq, c = c0 + cl;
    float acc = 0.f;
#pragma unroll
    for (int di = 0; di < 3; ++di)
#pragma unroll
      for (int dj = 0; dj < 3; ++dj)
        acc = fmaf(rb3[di][cl][w + dj], dww[c * 9 + di * 3 + dj], acc);
    float y = acc + dwb[c];
    float sc = bng[c] * rsqrtf(bnv[c] + 1e-5f);
    float v = (y - bnm[c]) * sc + bnb[c];
    sb[cl][w] = f2bf(v / (1.f + __expf(-v)));
  }
  __syncthreads();
#pragma unroll
  for (int i = 0; i < 4; ++i) {
    int wl = i * 16 + (tid >> 4);
    us4 r;
#pragma unroll
    for (int j = 0; j < 4; ++j) r[j] = sb[cb + j][wl];
    *reinterpret_cast<us4*>(&localT[((size_t)b * NN + n0 + wl) * CC + c0 + cb]) = r;
  }
}

// --------- fused Q,K,V projections (row-major outputs) + gate block (y==3)
__global__ __launch_bounds__(256, 4) void k_qkv(
    const unsigned short* __restrict__ XtS, const unsigned short* __restrict__ XtO,
    const unsigned short* __restrict__ Wb, const float* __restrict__ qb,
    const float* __restrict__ kvb, const float* __restrict__ psumA,
    const float* __restrict__ g1w, const float* __restrict__ g1b,
    const float* __restrict__ g2w, const float* __restrict__ g2b,
    unsigned short* __restrict__ Qt, unsigned short* __restrict__ Kt,
    unsigned short* __restrict__ Vv, float* __restrict__ gate) {
  __shared__ unsigned short Xs[64][264];   // stride 528B == 16 mod 128: conflict-free
  int tid = threadIdx.x;
  int id = blockIdx.y;
  if (id == 3) {                            // gate (SE path), one working block
    if (blockIdx.x != 0 || blockIdx.z != 0) return;
    float* mf = (float*)&Xs[0][0];          // 1024 f32 means
    float* hpf = mf + 1024;                 // 64*5
    int c = tid;
    for (int b4 = 0; b4 < 4; ++b4) {
      float s = 0.f;
      for (int hh = 0; hh < 64; ++hh) s += psumA[((size_t)(b4 * 64 + hh)) * CC + c];
      mf[b4 * 256 + c] = s * (1.f / 4096.f);
    }
    __syncthreads();
    for (int b4 = 0; b4 < 4; ++b4) {
      int j = tid >> 2, cq = tid & 3;
      float s = 0.f;
      for (int cc = cq * 64; cc < cq * 64 + 64; ++cc)
        s = fmaf(mf[b4 * 256 + cc], g1w[j * CC + cc], s);
      hpf[j * 5 + cq] = s;
      __syncthreads();
      if (tid < 64) {
        float hh = fmaxf(hpf[tid * 5] + hpf[tid * 5 + 1] + hpf[tid * 5 + 2] +
                             hpf[tid * 5 + 3] + g1b[tid], 0.f);
        float t = hh * g2w[tid];
        for (int off = 32; off; off >>= 1) t += __shfl_down(t, off, 64);
        if (tid == 0) gate[b4] = 1.f / (1.f + expf(-(t + g2b[0])));
      }
      __syncthreads();
    }
    return;
  }
  int n0 = blockIdx.x * 64, b = blockIdx.z;
  const unsigned short* Xt = (id == 0) ? XtS : XtO;
  const unsigned short* W = Wb + id * 65536;
  int wave = tid >> 6, lane = tid & 63, l31 = lane & 31, h = lane >> 5;
#pragma unroll
  for (int p = 0; p < 8; ++p) {
    int r = p * 8 + (tid >> 5), c = (tid & 31) * 8;
    *reinterpret_cast<uint4*>(&Xs[r][c]) =
        *reinterpret_cast<const uint4*>(Xt + ((size_t)b * NN + n0 + r) * CC + c);
  }
  __syncthreads();
  int o0 = wave * 64;
  f32x16 acc[4] = {};
  if (id < 2) {
#pragma unroll
    for (int t = 0; t < 16; ++t) {
      short8 a0 = ld8(&Xs[l31][t * 16 + h * 8]);
      short8 a1 = ld8(&Xs[32 + l31][t * 16 + h * 8]);
      short8 b0 = ld8(W + (size_t)(o0 + l31) * CC + t * 16 + h * 8);
      short8 b1 = ld8(W + (size_t)(o0 + 32 + l31) * CC + t * 16 + h * 8);
      acc[0] = __builtin_amdgcn_mfma_f32_32x32x16_bf16(a0, b0, acc[0], 0, 0, 0);
      acc[1] = __builtin_amdgcn_mfma_f32_32x32x16_bf16(a0, b1, acc[1], 0, 0, 0);
      acc[2] = __builtin_amdgcn_mfma_f32_32x32x16_bf16(a1, b0, acc[2], 0, 0, 0);
      acc[3] = __builtin_amdgcn_mfma_f32_32x32x16_bf16(a1, b1, acc[3], 0, 0, 0);
    }
    const float* bias = id ? kvb : qb;
    unsigned short* Out = id ? Kt : Qt;
    float scale = id ? 1.0f : 0.0625f;
#pragma unroll
    for (int nt = 0; nt < 2; ++nt)
#pragma unroll
      for (int ot = 0; ot < 2; ++ot) {
        int o = o0 + ot * 32 + l31;
        float bv = bias[o];
#pragma unroll
        for (int reg = 0; reg < 16; ++reg) {
          int n = n0 + nt * 32 + rowmap(reg, h);
          Out[((size_t)b * NN + n) * CC + o] = f2bf((acc[nt * 2 + ot][reg] + bv) * scale);
        }
      }
  } else {
    // V[o][n]: A = W rows (L2), B = Xt rows (LDS)
#pragma unroll
    for (int t = 0; t < 16; ++t) {
      short8 a0 = ld8(W + (size_t)(o0 + l31) * CC + t * 16 + h * 8);
      short8 a1 = ld8(W + (size_t)(o0 + 32 + l31) * CC + t * 16 + h * 8);
      short8 b0 = ld8(&Xs[l31][t * 16 + h * 8]);
      short8 b1 = ld8(&Xs[32 + l31][t * 16 + h * 8]);
      acc[0] = __builtin_amdgcn_mfma_f32_32x32x16_bf16(a0, b0, acc[0], 0, 0, 0);
      acc[1] = __builtin_amdgcn_mfma_f32_32x32x16_bf16(a0, b1, acc[1], 0, 0, 0);
      acc[2] = __builtin_amdgcn_mfma_f32_32x32x16_bf16(a1, b0, acc[2], 0, 0, 0);
      acc[3] = __builtin_amdgcn_mfma_f32_32x32x16_bf16(a1, b1, acc[3], 0, 0, 0);
    }
#pragma unroll
    for (int ot = 0; ot < 2; ++ot)
#pragma unroll
      for (int nt = 0; nt < 2; ++nt)
#pragma unroll
        for (int reg = 0; reg < 16; ++reg) {
          int o = o0 + ot * 32 + rowmap(reg, h);
          int n = n0 + nt * 32 + l31;
          Vv[((size_t)b * CC + o) * NN + n] = f2bf(acc[ot * 2 + nt][reg] + kvb[CC + o]);
        }
  }
}

// ------------- flash attention (proven round-2 structure) + XCD b-swizzle
__global__ __launch_bounds__(256, 2) void k_flash2(
    const unsigned short* __restrict__ Qt, const unsigned short* __restrict__ Kt,
    const unsigned short* __restrict__ V, const unsigned short* __restrict__ localT,
    const float* __restrict__ gate, float* __restrict__ Opart, float* __restrict__ Lpart,
    unsigned short* __restrict__ fusedT, int iters) {
  __shared__ unsigned short Ks[64][264];   // stride 528B == 16 mod 128
  __shared__ unsigned short Vs[256][72];   // stride 144B == 16 mod 128
  __shared__ unsigned short Ps[64][72];
  __shared__ float lred[2][64];
  __shared__ float ltot[64];
  // XCD swizzle: b = x&3 so each XCD's blocks share one b (K+V set = 4MB = L2)
  int b = blockIdx.x & 3, n0 = (blockIdx.x >> 2) * 64;
  int sp = blockIdx.y, nsp = gridDim.y;
  int tid = threadIdx.x, wave = tid >> 6, lane = tid & 63, l31 = lane & 31, h = lane >> 5;
  int rw = wave & 1, cw = wave >> 1;
  const unsigned short* qp = Qt + ((size_t)b * NN + n0 + rw * 32 + l31) * CC + h * 8;
  short8 qf[16];
#pragma unroll
  for (int t = 0; t < 16; ++t) qf[t] = ld8(qp + t * 16);
  f32x16 O[4] = {};
  float lacc[16] = {};
  int mbase = sp * iters * 64;
  for (int it = 0; it < iters; ++it) {
    int m0 = mbase + it * 64;
    __syncthreads();
#pragma unroll
    for (int p = 0; p < 8; ++p) {
      int m = p * 8 + (tid >> 5), ccol = (tid & 31) * 8;
      *reinterpret_cast<uint4*>(&Ks[m][ccol]) =
          *reinterpret_cast<const uint4*>(Kt + ((size_t)b * NN + m0 + m) * CC + ccol);
    }
#pragma unroll
    for (int p = 0; p < 8; ++p) {
      int ccol = p * 32 + (tid >> 3), mm = (tid & 7) * 8;
      *reinterpret_cast<uint4*>(&Vs[ccol][mm]) =
          *reinterpret_cast<const uint4*>(V + ((size_t)b * CC + ccol) * NN + m0 + mm);
    }
    __syncthreads();
    f32x16 S = {};
#pragma unroll
    for (int t = 0; t < 16; ++t) {
      short8 kf = ld8(&Ks[cw * 32 + l31][t * 16 + h * 8]);
      S = __builtin_amdgcn_mfma_f32_32x32x16_bf16(qf[t], kf, S, 0, 0, 0);
    }
#pragma unroll
    for (int reg = 0; reg < 16; ++reg) {
      float p = __builtin_exp2f(S[reg] * LOG2E);
      lacc[reg] += p;
      Ps[rw * 32 + rowmap(reg, h)][cw * 32 + l31] = f2bf(p);
    }
    __syncthreads();
#pragma unroll
    for (int t = 0; t < 4; ++t) {
      short8 pf = ld8(&Ps[rw * 32 + l31][t * 16 + h * 8]);
#pragma unroll
      for (int ct = 0; ct < 4; ++ct) {
        short8 vf = ld8(&Vs[cw * 128 + ct * 32 + l31][t * 16 + h * 8]);
        O[ct] = __builtin_amdgcn_mfma_f32_32x32x16_bf16(pf, vf, O[ct], 0, 0, 0);
      }
    }
  }
#pragma unroll
  for (int reg = 0; reg < 16; ++reg) {
    float v = lacc[reg];
#pragma unroll
    for (int msk = 1; msk < 32; msk <<= 1) v += __shfl_xor(v, msk, 64);
    lacc[reg] = v;
  }
  __syncthreads();
#pragma unroll
  for (int g = 0; g < 16; ++g)
    if (l31 == g) lred[cw][rw * 32 + rowmap(g, h)] = lacc[g];
  __syncthreads();
  size_t obase2 = (size_t)(b * nsp + sp) * NN;
  if (nsp == 1) {
    if (tid < 64) ltot[tid] = lred[0][tid] + lred[1][tid];
    __syncthreads();
    float gv = gate[b];
    float inv[16];
#pragma unroll
    for (int reg = 0; reg < 16; ++reg)
      inv[reg] = gv / ltot[rw * 32 + rowmap(reg, h)];
#pragma unroll
    for (int ct = 0; ct < 4; ++ct)
#pragma unroll
      for (int reg = 0; reg < 16; ++reg) {
        int n = n0 + rw * 32 + rowmap(reg, h);
        int c = cw * 128 + ct * 32 + l31;
        size_t idx = ((size_t)b * NN + n) * CC + c;
        fusedT[idx] = f2bf(bf2f(localT[idx]) + O[ct][reg] * inv[reg]);
      }
  } else {
    if (tid < 64) Lpart[obase2 + n0 + tid] = lred[0][tid] + lred[1][tid];
#pragma unroll
    for (int ct = 0; ct < 4; ++ct)
#pragma unroll
      for (int reg = 0; reg < 16; ++reg) {
        int n = n0 + rw * 32 + rowmap(reg, h);
        int c = cw * 128 + ct * 32 + l31;
        Opart[(obase2 + n) * CC + c] = O[ct][reg];
      }
  }
}

// --------- out projection with fused split-combine in the staging phase
__global__ __launch_bounds__(256, 4) void k_out(
    const unsigned short* __restrict__ W, const float* __restrict__ ob,
    const float* __restrict__ gate, const unsigned short* __restrict__ localT,
    const float* __restrict__ Opart, const float* __restrict__ Lpart,
    const unsigned short* __restrict__ fusedT, float* __restrict__ out, int nsp) {
  __shared__ unsigned short Xs[64][264];
  int n0 = blockIdx.x * 64, o0 = blockIdx.y * 128, b = blockIdx.z;
  int tid = threadIdx.x, wave = tid >> 6, lane = tid & 63, l31 = lane & 31, h = lane >> 5;
  if (Opart) {
    float gv = gate[b];
#pragma unroll
    for (int p = 0; p < 8; ++p) {
      int r = p * 8 + (tid >> 5), cc = (tid & 31) * 8;
      int n = n0 + r;
      float lsum = 0.f;
      for (int sp = 0; sp < nsp; ++sp) lsum += Lpart[(size_t)(b * nsp + sp) * NN + n];
      float g = gv / lsum;
      f32x4 o0v = {}, o1v = {};
      for (int sp = 0; sp < nsp; ++sp) {
        const float* op = &Opart[((size_t)(b * nsp + sp) * NN + n) * CC + cc];
        o0v += *reinterpret_cast<const f32x4*>(op);
        o1v += *reinterpret_cast<const f32x4*>(op + 4);
      }
      const unsigned short* lp = localT + ((size_t)b * NN + n) * CC + cc;
      us4 l0 = *reinterpret_cast<const us4*>(lp), l1 = *reinterpret_cast<const us4*>(lp + 4);
      us4 r0, r1;
#pragma unroll
      for (int j = 0; j < 4; ++j) {
        r0[j] = f2bf(bf2f(l0[j]) + o0v[j] * g);
        r1[j] = f2bf(bf2f(l1[j]) + o1v[j] * g);
      }
      *reinterpret_cast<us4*>(&Xs[r][cc]) = r0;
      *reinterpret_cast<us4*>(&Xs[r][cc + 4]) = r1;
    }
  } else {
#pragma unroll
    for (int p = 0; p < 8; ++p) {
      int r = p * 8 + (tid >> 5), c = (tid & 31) * 8;
      *reinterpret_cast<uint4*>(&Xs[r][c]) =
          *reinterpret_cast<const uint4*>(fusedT + ((size_t)b * NN + n0 + r) * CC + c);
    }
  }
  int obase = o0 + wave * 32;
  short8 af[16];
#pragma unroll
  for (int t = 0; t < 16; ++t) af[t] = ld8(W + (size_t)(obase + l31) * CC + t * 16 + h * 8);
  __syncthreads();
  f32x16 acc[2] = {};
#pragma unroll
  for (int t = 0; t < 16; ++t) {
    short8 b0 = ld8(&Xs[l31][t * 16 + h * 8]);
    short8 b1 = ld8(&Xs[32 + l31][t * 16 + h * 8]);
    acc[0] = __builtin_amdgcn_mfma_f32_32x32x16_bf16(af[t], b0, acc[0], 0, 0, 0);
    acc[1] = __builtin_amdgcn_mfma_f32_32x32x16_bf16(af[t], b1, acc[1], 0, 0, 0);
  }
#pragma unroll
  for (int nt = 0; nt < 2; ++nt)
#pragma unroll
    for (int reg = 0; reg < 16; ++reg) {
      int o = obase + rowmap(reg, h);
      int n = n0 + nt * 32 + l31;
      out[((size_t)b * CC + o) * NN + n] = acc[nt][reg] + ob[o];
    }
}

// ---------------------------------------------------------------------------- launch
extern "C" void kernel_launch(void* const* d_in, const int* in_sizes, int n_in,
                              void* d_out, int out_size, void* d_ws, size_t ws_size,
                              hipStream_t stream) {
  const float* xs  = (const float*)d_in[0];
  const float* xo  = (const float*)d_in[1];
  const float* qw  = (const float*)d_in[2];
  const float* qb  = (const float*)d_in[3];
  const float* kvw = (const float*)d_in[4];
  const float* kvb = (const float*)d_in[5];
  const float* g1w = (const float*)d_in[6];
  const float* g1b = (const float*)d_in[7];
  const float* g2w = (const float*)d_in[8];
  const float* g2b = (const float*)d_in[9];
  const float* dww = (const float*)d_in[10];
  const float* dwb = (const float*)d_in[11];
  const float* bng = (const float*)d_in[12];
  const float* bnb = (const float*)d_in[13];
  const float* bnm = (const float*)d_in[14];
  const float* bnv = (const float*)d_in[15];
  const float* ow  = (const float*)d_in[16];
  const float* ob  = (const float*)d_in[17];
  float* out = (float*)d_out;
  char* ws = (char*)d_ws;

  const size_t SZ = (size_t)BB * NN * CC * 2;             // 8 MB per bf16 tensor
  unsigned short* XtS    = (unsigned short*)(ws);         // -> fusedT alias (S=1 path)
  unsigned short* XtO    = (unsigned short*)(ws + SZ);
  unsigned short* Qt     = (unsigned short*)(ws + 2 * SZ);
  unsigned short* Kt     = (unsigned short*)(ws + 3 * SZ);
  unsigned short* Vv     = (unsigned short*)(ws + 4 * SZ);
  unsigned short* localT = (unsigned short*)(ws + 5 * SZ);  // dedicated
  unsigned short* Wb     = (unsigned short*)(ws + 6 * SZ);  // 512 KB
  float* psumA = (float*)(ws + 6 * SZ + 524288);            // 256 KB partials
  float* gate  = (float*)(ws + 6 * SZ + 524288 + 262144);   // 16 B
  size_t tail  = 6 * SZ + 524288 + 262144 + 4096;
  float* Lpart = (float*)(ws + tail);                       // 128 KB (S=2)
  float* Opart = (float*)(ws + tail + 131072);              // 32 MB (S=2)
  unsigned short* fusedT = XtS;                             // dead after k_qkv

  size_t need2 = tail + 131072 + 2ull * 16777216;
  int S = (ws_size >= need2) ? 2 : 1;

  k_pre<<<dim3(4, 64, 9), 256, 0, stream>>>(xs, xo, dww, dwb, bng, bnb, bnm, bnv,
                                            qw, kvw, ow, XtS, XtO, localT, psumA, Wb);
  k_qkv<<<dim3(64, 4, 4), 256, 0, stream>>>(XtS, XtO, Wb, qb, kvb, psumA,
                                            g1w, g1b, g2w, g2b, Qt, Kt, Vv, gate);
  k_flash2<<<dim3(256, S), 256, 0, stream>>>(Qt, Kt, Vv, localT, gate, Opart, Lpart,
                                             fusedT, 64 / S);
  k_out<<<dim3(64, 2, 4), 256, 0, stream>>>(Wb + 196608, ob, gate, localT,
                                            S > 1 ? Opart : nullptr, Lpart, fusedT,
                                            out, S);
}

// Round 6
// 251.617 us; speedup vs baseline: 1.6525x; 1.1241x over previous
//
#include <hip/hip_runtime.h>
#include <stdint.h>

#define BB 4
#define CC 256
#define HH 64
#define WWD 64
#define NN 4096
#define LOG2E 1.4426950408889634f

typedef __attribute__((ext_vector_type(8))) short short8;
typedef __attribute__((ext_vector_type(4))) float f32x4;
typedef __attribute__((ext_vector_type(16))) float f32x16;
typedef __attribute__((ext_vector_type(4))) unsigned short us4;
typedef unsigned long long ull;

__device__ __forceinline__ unsigned short f2bf(float f) {
  unsigned int u = __float_as_uint(f);
  u += 0x7fffu + ((u >> 16) & 1u);          // RNE
  return (unsigned short)(u >> 16);
}
__device__ __forceinline__ float bf2f(unsigned short h) {
  return __uint_as_float(((unsigned int)h) << 16);
}
__device__ __forceinline__ short8 ld8(const unsigned short* p) {
  return *reinterpret_cast<const short8*>(p);
}
__device__ __forceinline__ unsigned char f2fp8(float v) {   // OCP e4m3 via HW cvt (RNE)
  return (unsigned char)__builtin_amdgcn_cvt_pk_fp8_f32(v, v, 0, false);
}
__device__ __forceinline__ int rowmap(int reg, int h) {     // 32x32 C/D row map
  return (reg & 3) + 8 * (reg >> 2) + 4 * h;
}

// ---------------- k_pre: z<8 -> transpose (+psum partials, +dwconv for x_self);
//                  z==8 -> weight fp32->bf16 cast slice
__global__ __launch_bounds__(256, 2) void k_pre(
    const float* __restrict__ xs, const float* __restrict__ xo,
    const float* __restrict__ dww, const float* __restrict__ dwb,
    const float* __restrict__ bng, const float* __restrict__ bnb,
    const float* __restrict__ bnm, const float* __restrict__ bnv,
    const float* __restrict__ qw, const float* __restrict__ kvw,
    const float* __restrict__ ow, unsigned short* __restrict__ XtS,
    unsigned short* __restrict__ XtO, unsigned short* __restrict__ localT,
    float* __restrict__ psumA, unsigned short* __restrict__ Wb) {
  __shared__ float rb3[3][64][67];
  __shared__ unsigned short sb[64][67];
  int tid = threadIdx.x;
  if (blockIdx.z == 8) {                    // weight cast
    int i = (blockIdx.x * 64 + blockIdx.y) * 1024 + tid * 4;
    const float* src;
    if (i < 65536) src = qw + i;
    else if (i < 196608) src = kvw + (i - 65536);
    else src = ow + (i - 196608);
    f32x4 v = *reinterpret_cast<const f32x4*>(src);
    us4 r;
#pragma unroll
    for (int j = 0; j < 4; ++j) r[j] = f2bf(v[j]);
    *reinterpret_cast<us4*>(Wb + i) = r;
    return;
  }
  int c0 = blockIdx.x * 64, h = blockIdx.y;
  int b = blockIdx.z >> 1, which = blockIdx.z & 1;
  const float* src = which ? xo : xs;
  int wq = tid >> 6, w = tid & 63;
  int dlo = which ? 1 : 0, dhi = which ? 1 : 2;
  for (int d = dlo; d <= dhi; ++d) {
    int hh = h + d - 1;
    bool ok = (hh >= 0 && hh < HH);
#pragma unroll
    for (int p = 0; p < 4; ++p) {
      int idx = p * 256 + tid;
      int cl = idx >> 4, ws4 = (idx & 15) * 4;
      f32x4 v = {};
      if (ok)
        v = *reinterpret_cast<const f32x4*>(
            &src[(((size_t)(b * CC + c0 + cl)) * HH + hh) * WWD + ws4]);
#pragma unroll
      for (int j = 0; j < 4; ++j) rb3[d][cl][ws4 + 1 + j] = v[j];
    }
    if (tid < 64) { rb3[d][tid][0] = 0.f; rb3[d][tid][65] = 0.f; }
  }
  __syncthreads();
  // transpose-store middle row -> Xt
  unsigned short* dst = which ? XtO : XtS;
  int n0 = h * 64, cb = (tid & 15) * 4;
#pragma unroll
  for (int i = 0; i < 4; ++i) {
    int wl = i * 16 + (tid >> 4);
    us4 r;
#pragma unroll
    for (int j = 0; j < 4; ++j) r[j] = f2bf(rb3[1][cb + j][wl + 1]);
    *reinterpret_cast<us4*>(&dst[((size_t)b * NN + n0 + wl) * CC + c0 + cb]) = r;
  }
  if (which) return;
  if (tid < 64) {                           // channel-sum partial
    float s = 0.f;
    for (int ww = 0; ww < 64; ++ww) s += rb3[1][tid][ww + 1];
    psumA[((size_t)(b * 64 + h)) * CC + c0 + tid] = s;
  }
  // depthwise 3x3 + BN + SiLU
  for (int p = 0; p < 16; ++p) {
    int cl = p * 4 + wq, c = c0 + cl;
    float acc = 0.f;
#pragma unroll
    for (int di = 0; di < 3; ++di)
#pragma unroll
      for (int dj = 0; dj < 3; ++dj)
        acc = fmaf(rb3[di][cl][w + dj], dww[c * 9 + di * 3 + dj], acc);
    float y = acc + dwb[c];
    float sc = bng[c] * rsqrtf(bnv[c] + 1e-5f);
    float v = (y - bnm[c]) * sc + bnb[c];
    sb[cl][w] = f2bf(v / (1.f + __expf(-v)));
  }
  __syncthreads();
#pragma unroll
  for (int i = 0; i < 4; ++i) {
    int wl = i * 16 + (tid >> 4);
    us4 r;
#pragma unroll
    for (int j = 0; j < 4; ++j) r[j] = sb[cb + j][wl];
    *reinterpret_cast<us4*>(&localT[((size_t)b * NN + h * WWD + wl) * CC + c0 + cb]) = r;
  }
}

// --------- fused Q,K,V projections -> fp8 outputs (LDS-transposed, coalesced);
//           + gate block (y==3). Q,K carry sqrt-split softmax scale (0.25 each).
__global__ __launch_bounds__(256, 4) void k_qkv(
    const unsigned short* __restrict__ XtS, const unsigned short* __restrict__ XtO,
    const unsigned short* __restrict__ Wb, const float* __restrict__ qb,
    const float* __restrict__ kvb, const float* __restrict__ psumA,
    const float* __restrict__ g1w, const float* __restrict__ g1b,
    const float* __restrict__ g2w, const float* __restrict__ g2b,
    unsigned char* __restrict__ Qt8, unsigned char* __restrict__ Kt8,
    unsigned char* __restrict__ Vv8, float* __restrict__ gate) {
  __shared__ unsigned short Xs[64][264];   // 33.8 KB; reused as fp8 transpose buffer
  int tid = threadIdx.x;
  int id = blockIdx.y;
  if (id == 3) {                            // gate (SE path), one working block
    if (blockIdx.x != 0 || blockIdx.z != 0) return;
    float* mf = (float*)&Xs[0][0];
    float* hpf = mf + 1024;
    int c = tid;
    for (int b4 = 0; b4 < 4; ++b4) {
      float s = 0.f;
      for (int hh = 0; hh < 64; ++hh) s += psumA[((size_t)(b4 * 64 + hh)) * CC + c];
      mf[b4 * 256 + c] = s * (1.f / 4096.f);
    }
    __syncthreads();
    for (int b4 = 0; b4 < 4; ++b4) {
      int j = tid >> 2, cq = tid & 3;
      float s = 0.f;
      for (int cc = cq * 64; cc < cq * 64 + 64; ++cc)
        s = fmaf(mf[b4 * 256 + cc], g1w[j * CC + cc], s);
      hpf[j * 5 + cq] = s;
      __syncthreads();
      if (tid < 64) {
        float hh = fmaxf(hpf[tid * 5] + hpf[tid * 5 + 1] + hpf[tid * 5 + 2] +
                             hpf[tid * 5 + 3] + g1b[tid], 0.f);
        float t = hh * g2w[tid];
        for (int off = 32; off; off >>= 1) t += __shfl_down(t, off, 64);
        if (tid == 0) gate[b4] = 1.f / (1.f + expf(-(t + g2b[0])));
      }
      __syncthreads();
    }
    return;
  }
  int n0 = blockIdx.x * 64, b = blockIdx.z;
  const unsigned short* Xt = (id == 0) ? XtS : XtO;
  const unsigned short* W = Wb + id * 65536;
  int wave = tid >> 6, lane = tid & 63, l31 = lane & 31, h = lane >> 5;
#pragma unroll
  for (int p = 0; p < 8; ++p) {
    int r = p * 8 + (tid >> 5), c = (tid & 31) * 8;
    *reinterpret_cast<uint4*>(&Xs[r][c]) =
        *reinterpret_cast<const uint4*>(Xt + ((size_t)b * NN + n0 + r) * CC + c);
  }
  __syncthreads();
  int o0 = wave * 64;
  f32x16 acc[4] = {};
  if (id < 2) {
#pragma unroll
    for (int t = 0; t < 16; ++t) {
      short8 a0 = ld8(&Xs[l31][t * 16 + h * 8]);
      short8 a1 = ld8(&Xs[32 + l31][t * 16 + h * 8]);
      short8 b0 = ld8(W + (size_t)(o0 + l31) * CC + t * 16 + h * 8);
      short8 b1 = ld8(W + (size_t)(o0 + 32 + l31) * CC + t * 16 + h * 8);
      acc[0] = __builtin_amdgcn_mfma_f32_32x32x16_bf16(a0, b0, acc[0], 0, 0, 0);
      acc[1] = __builtin_amdgcn_mfma_f32_32x32x16_bf16(a0, b1, acc[1], 0, 0, 0);
      acc[2] = __builtin_amdgcn_mfma_f32_32x32x16_bf16(a1, b0, acc[2], 0, 0, 0);
      acc[3] = __builtin_amdgcn_mfma_f32_32x32x16_bf16(a1, b1, acc[3], 0, 0, 0);
    }
    const float* bias = id ? kvb : qb;
    unsigned char* Out8 = id ? Kt8 : Qt8;
    __syncthreads();                        // Xs MFMA reads done
    unsigned char (*T8)[264] = reinterpret_cast<unsigned char(*)[264]>(&Xs[0][0]);
#pragma unroll
    for (int nt = 0; nt < 2; ++nt)
#pragma unroll
      for (int ot = 0; ot < 2; ++ot) {
        int o = o0 + ot * 32 + l31;
        float bv = bias[o];
#pragma unroll
        for (int reg = 0; reg < 16; ++reg) {
          int nl = nt * 32 + rowmap(reg, h);
          T8[nl][o] = f2fp8((acc[nt * 2 + ot][reg] + bv) * 0.25f);
        }
      }
    __syncthreads();
#pragma unroll
    for (int p = 0; p < 4; ++p) {
      int idx = p * 256 + tid, row = idx >> 4, cc = (idx & 15) * 16;
      ull a0 = *reinterpret_cast<const ull*>(&T8[row][cc]);
      ull a1 = *reinterpret_cast<const ull*>(&T8[row][cc + 8]);
      uint4 u;
      u.x = (unsigned)a0; u.y = (unsigned)(a0 >> 32);
      u.z = (unsigned)a1; u.w = (unsigned)(a1 >> 32);
      *reinterpret_cast<uint4*>(Out8 + ((size_t)b * NN + n0 + row) * CC + cc) = u;
    }
  } else {
    // V[o][n]
#pragma unroll
    for (int t = 0; t < 16; ++t) {
      short8 a0 = ld8(W + (size_t)(o0 + l31) * CC + t * 16 + h * 8);
      short8 a1 = ld8(W + (size_t)(o0 + 32 + l31) * CC + t * 16 + h * 8);
      short8 b0 = ld8(&Xs[l31][t * 16 + h * 8]);
      short8 b1 = ld8(&Xs[32 + l31][t * 16 + h * 8]);
      acc[0] = __builtin_amdgcn_mfma_f32_32x32x16_bf16(a0, b0, acc[0], 0, 0, 0);
      acc[1] = __builtin_amdgcn_mfma_f32_32x32x16_bf16(a0, b1, acc[1], 0, 0, 0);
      acc[2] = __builtin_amdgcn_mfma_f32_32x32x16_bf16(a1, b0, acc[2], 0, 0, 0);
      acc[3] = __builtin_amdgcn_mfma_f32_32x32x16_bf16(a1, b1, acc[3], 0, 0, 0);
    }
    __syncthreads();
    unsigned char (*V8)[72] = reinterpret_cast<unsigned char(*)[72]>(&Xs[0][0]);
#pragma unroll
    for (int ot = 0; ot < 2; ++ot)
#pragma unroll
      for (int nt = 0; nt < 2; ++nt)
#pragma unroll
        for (int reg = 0; reg < 16; ++reg) {
          int o = o0 + ot * 32 + rowmap(reg, h);
          int nl = nt * 32 + l31;
          V8[o][nl] = f2fp8(acc[ot * 2 + nt][reg] + kvb[CC + o]);
        }
    __syncthreads();
#pragma unroll
    for (int p = 0; p < 4; ++p) {
      int idx = p * 256 + tid, o = idx >> 2, mm = (idx & 3) * 16;
      ull a0 = *reinterpret_cast<const ull*>(&V8[o][mm]);
      ull a1 = *reinterpret_cast<const ull*>(&V8[o][mm + 8]);
      uint4 u;
      u.x = (unsigned)a0; u.y = (unsigned)(a0 >> 32);
      u.z = (unsigned)a1; u.w = (unsigned)(a1 >> 32);
      *reinterpret_cast<uint4*>(Vv8 + ((size_t)b * CC + o) * NN + n0 + mm) = u;
    }
  }
}

// ------------- flash attention, fp8 e4m3 everywhere (Q,K,V,P). LDS 40.7 KB -> 3 blk/CU.
__global__ __launch_bounds__(256, 3) void k_flash8(
    const unsigned char* __restrict__ Qt8, const unsigned char* __restrict__ Kt8,
    const unsigned char* __restrict__ Vv8, const unsigned short* __restrict__ localT,
    const float* __restrict__ gate, unsigned short* __restrict__ Opart16,
    float* __restrict__ Lpart, unsigned short* __restrict__ fusedT) {
  __shared__ unsigned char Ks8[64][264];   // 264 % 128 == 8: 2-way (free) b64 reads
  __shared__ unsigned char Vs8[256][72];   // 72: 2-way (free)
  __shared__ unsigned char Ps8[64][72];
  __shared__ float lred[2][64];
  __shared__ float ltot[64];
  // XCD swizzle: b = x&3 -> each XCD pinned to one b; K+V fp8 = 2 MB, L2-resident
  int b = blockIdx.x & 3, n0 = (blockIdx.x >> 2) * 64;
  int sp = blockIdx.y, nsp = gridDim.y;
  int tid = threadIdx.x, wave = tid >> 6, lane = tid & 63, l31 = lane & 31, h = lane >> 5;
  int rw = wave & 1, cw = wave >> 1;
  const unsigned char* qp = Qt8 + ((size_t)b * NN + n0 + rw * 32 + l31) * CC + h * 8;
  long qf[16];
#pragma unroll
  for (int t = 0; t < 16; ++t) qf[t] = *reinterpret_cast<const long*>(qp + t * 16);
  f32x16 O[4] = {};
  float lacc[16] = {};
  int m_lo = (64 * sp) / nsp, m_hi = (64 * (sp + 1)) / nsp;
  for (int mt = m_lo; mt < m_hi; ++mt) {
    int m0 = mt * 64;
    __syncthreads();          // prior iter's Vs/Ps/Ks reads complete
    // stage K tile (64m x 256c fp8, coalesced 1KB/wave)
#pragma unroll
    for (int p = 0; p < 4; ++p) {
      int idx = p * 256 + tid, m = idx >> 4, cc = (idx & 15) * 16;
      const ull* gp = reinterpret_cast<const ull*>(Kt8 + ((size_t)b * NN + m0 + m) * CC + cc);
      ull a0 = gp[0], a1 = gp[1];
      *reinterpret_cast<ull*>(&Ks8[m][cc]) = a0;
      *reinterpret_cast<ull*>(&Ks8[m][cc + 8]) = a1;
    }
    // stage V tile (256c x 64m fp8)
#pragma unroll
    for (int p = 0; p < 4; ++p) {
      int idx = p * 256 + tid, c = idx >> 2, mm = (idx & 3) * 16;
      const ull* gp = reinterpret_cast<const ull*>(Vv8 + ((size_t)b * CC + c) * NN + m0 + mm);
      ull a0 = gp[0], a1 = gp[1];
      *reinterpret_cast<ull*>(&Vs8[c][mm]) = a0;
      *reinterpret_cast<ull*>(&Vs8[c][mm + 8]) = a1;
    }
    __syncthreads();
    // S = Q K^T (32x32 per wave, K=256 via 16 fp8 MFMAs)
    f32x16 S = {};
#pragma unroll
    for (int t = 0; t < 16; ++t) {
      long kf = *reinterpret_cast<const long*>(&Ks8[cw * 32 + l31][t * 16 + h * 8]);
      S = __builtin_amdgcn_mfma_f32_32x32x16_fp8_fp8(qf[t], kf, S, 0, 0, 0);
    }
    // P = exp(S) -> fp8; row-sum accumulate
#pragma unroll
    for (int reg = 0; reg < 16; ++reg) {
      float p = __builtin_exp2f(S[reg] * LOG2E);
      lacc[reg] += p;
      Ps8[rw * 32 + rowmap(reg, h)][cw * 32 + l31] = f2fp8(p);
    }
    __syncthreads();
    // O += P V^T : rows rw*32, cols cw*128, k=64 via 4 fp8 MFMAs per col-tile
#pragma unroll
    for (int t = 0; t < 4; ++t) {
      long pf = *reinterpret_cast<const long*>(&Ps8[rw * 32 + l31][t * 16 + h * 8]);
#pragma unroll
      for (int ct = 0; ct < 4; ++ct) {
        long vf = *reinterpret_cast<const long*>(&Vs8[cw * 128 + ct * 32 + l31][t * 16 + h * 8]);
        O[ct] = __builtin_amdgcn_mfma_f32_32x32x16_fp8_fp8(pf, vf, O[ct], 0, 0, 0);
      }
    }
  }
#pragma unroll
  for (int reg = 0; reg < 16; ++reg) {
    float v = lacc[reg];
#pragma unroll
    for (int msk = 1; msk < 32; msk <<= 1) v += __shfl_xor(v, msk, 64);
    lacc[reg] = v;
  }
  __syncthreads();
#pragma unroll
  for (int g = 0; g < 16; ++g)
    if (l31 == g) lred[cw][rw * 32 + rowmap(g, h)] = lacc[g];
  __syncthreads();
  size_t obase2 = (size_t)(b * nsp + sp) * NN;
  if (nsp == 1) {
    if (tid < 64) ltot[tid] = lred[0][tid] + lred[1][tid];
    __syncthreads();
    float gv = gate[b];
    float inv[16];
#pragma unroll
    for (int reg = 0; reg < 16; ++reg)
      inv[reg] = gv / ltot[rw * 32 + rowmap(reg, h)];
#pragma unroll
    for (int ct = 0; ct < 4; ++ct)
#pragma unroll
      for (int reg = 0; reg < 16; ++reg) {
        int n = n0 + rw * 32 + rowmap(reg, h);
        int c = cw * 128 + ct * 32 + l31;
        size_t idx = ((size_t)b * NN + n) * CC + c;
        fusedT[idx] = f2bf(bf2f(localT[idx]) + O[ct][reg] * inv[reg]);
      }
  } else {
    if (tid < 64) Lpart[obase2 + n0 + tid] = lred[0][tid] + lred[1][tid];
#pragma unroll
    for (int ct = 0; ct < 4; ++ct)
#pragma unroll
      for (int reg = 0; reg < 16; ++reg) {
        int n = n0 + rw * 32 + rowmap(reg, h);
        int c = cw * 128 + ct * 32 + l31;
        Opart16[(obase2 + n) * CC + c] = f2bf(O[ct][reg]);
      }
  }
}

// --------- out projection with fused split-combine (Opart bf16)
__global__ __launch_bounds__(256, 4) void k_out(
    const unsigned short* __restrict__ W, const float* __restrict__ ob,
    const float* __restrict__ gate, const unsigned short* __restrict__ localT,
    const unsigned short* __restrict__ Opart16, const float* __restrict__ Lpart,
    const unsigned short* __restrict__ fusedT, float* __restrict__ out, int nsp) {
  __shared__ unsigned short Xs[64][264];
  int n0 = blockIdx.x * 64, o0 = blockIdx.y * 128, b = blockIdx.z;
  int tid = threadIdx.x, wave = tid >> 6, lane = tid & 63, l31 = lane & 31, h = lane >> 5;
  if (Opart16) {
    float gv = gate[b];
#pragma unroll
    for (int p = 0; p < 8; ++p) {
      int r = p * 8 + (tid >> 5), cc = (tid & 31) * 8;
      int n = n0 + r;
      float lsum = 0.f;
      for (int sp = 0; sp < nsp; ++sp) lsum += Lpart[(size_t)(b * nsp + sp) * NN + n];
      float g = gv / lsum;
      float ov[8] = {};
      for (int sp = 0; sp < nsp; ++sp) {
        short8 x = ld8(Opart16 + ((size_t)(b * nsp + sp) * NN + n) * CC + cc);
#pragma unroll
        for (int j = 0; j < 8; ++j) ov[j] += bf2f(((unsigned short*)&x)[j]);
      }
      const unsigned short* lp = localT + ((size_t)b * NN + n) * CC + cc;
      short8 lv = ld8(lp);
      us4 r0, r1;
#pragma unroll
      for (int j = 0; j < 4; ++j) {
        r0[j] = f2bf(bf2f(((unsigned short*)&lv)[j]) + ov[j] * g);
        r1[j] = f2bf(bf2f(((unsigned short*)&lv)[j + 4]) + ov[j + 4] * g);
      }
      *reinterpret_cast<us4*>(&Xs[r][cc]) = r0;
      *reinterpret_cast<us4*>(&Xs[r][cc + 4]) = r1;
    }
  } else {
#pragma unroll
    for (int p = 0; p < 8; ++p) {
      int r = p * 8 + (tid >> 5), c = (tid & 31) * 8;
      *reinterpret_cast<uint4*>(&Xs[r][c]) =
          *reinterpret_cast<const uint4*>(fusedT + ((size_t)b * NN + n0 + r) * CC + c);
    }
  }
  int obase = o0 + wave * 32;
  short8 af[16];
#pragma unroll
  for (int t = 0; t < 16; ++t) af[t] = ld8(W + (size_t)(obase + l31) * CC + t * 16 + h * 8);
  __syncthreads();
  f32x16 acc[2] = {};
#pragma unroll
  for (int t = 0; t < 16; ++t) {
    short8 b0 = ld8(&Xs[l31][t * 16 + h * 8]);
    short8 b1 = ld8(&Xs[32 + l31][t * 16 + h * 8]);
    acc[0] = __builtin_amdgcn_mfma_f32_32x32x16_bf16(af[t], b0, acc[0], 0, 0, 0);
    acc[1] = __builtin_amdgcn_mfma_f32_32x32x16_bf16(af[t], b1, acc[1], 0, 0, 0);
  }
#pragma unroll
  for (int nt = 0; nt < 2; ++nt)
#pragma unroll
    for (int reg = 0; reg < 16; ++reg) {
      int o = obase + rowmap(reg, h);
      int n = n0 + nt * 32 + l31;
      out[((size_t)b * CC + o) * NN + n] = acc[nt][reg] + ob[o];
    }
}

// ---------------------------------------------------------------------------- launch
extern "C" void kernel_launch(void* const* d_in, const int* in_sizes, int n_in,
                              void* d_out, int out_size, void* d_ws, size_t ws_size,
                              hipStream_t stream) {
  const float* xs  = (const float*)d_in[0];
  const float* xo  = (const float*)d_in[1];
  const float* qw  = (const float*)d_in[2];
  const float* qb  = (const float*)d_in[3];
  const float* kvw = (const float*)d_in[4];
  const float* kvb = (const float*)d_in[5];
  const float* g1w = (const float*)d_in[6];
  const float* g1b = (const float*)d_in[7];
  const float* g2w = (const float*)d_in[8];
  const float* g2b = (const float*)d_in[9];
  const float* dww = (const float*)d_in[10];
  const float* dwb = (const float*)d_in[11];
  const float* bng = (const float*)d_in[12];
  const float* bnb = (const float*)d_in[13];
  const float* bnm = (const float*)d_in[14];
  const float* bnv = (const float*)d_in[15];
  const float* ow  = (const float*)d_in[16];
  const float* ob  = (const float*)d_in[17];
  float* out = (float*)d_out;
  char* ws = (char*)d_ws;

  const size_t SZ  = (size_t)BB * NN * CC * 2;            // 8 MB bf16 tensor
  const size_t SZ8 = (size_t)BB * NN * CC;                // 4 MB fp8 tensor
  unsigned short* XtS    = (unsigned short*)(ws);
  unsigned short* XtO    = (unsigned short*)(ws + SZ);
  unsigned short* localT = (unsigned short*)(ws + 2 * SZ);
  unsigned char*  Qt8    = (unsigned char*)(ws + 3 * SZ);
  unsigned char*  Kt8    = (unsigned char*)(ws + 3 * SZ + SZ8);
  unsigned char*  Vv8    = (unsigned char*)(ws + 3 * SZ + 2 * SZ8);
  unsigned short* Wb     = (unsigned short*)(ws + 3 * SZ + 3 * SZ8);   // 512 KB
  float* psumA = (float*)(ws + 3 * SZ + 3 * SZ8 + 524288);             // 256 KB
  float* gate  = (float*)(ws + 3 * SZ + 3 * SZ8 + 524288 + 262144);    // 16 B
  size_t tail  = 3 * SZ + 3 * SZ8 + 524288 + 262144 + 4096;
  float* Lpart = (float*)(ws + tail);                                  // 256 KB
  unsigned short* Opart16 = (unsigned short*)(ws + tail + 262144);     // nsp*8 MB
  unsigned short* fusedT = XtS;                                        // dead after k_qkv

  size_t base = tail + 262144;
  int S = 1;
  if (ws_size >= base + 3ull * SZ) S = 3;          // 768 blocks = 3/CU
  else if (ws_size >= base + 2ull * SZ) S = 2;

  k_pre<<<dim3(4, 64, 9), 256, 0, stream>>>(xs, xo, dww, dwb, bng, bnb, bnm, bnv,
                                            qw, kvw, ow, XtS, XtO, localT, psumA, Wb);
  k_qkv<<<dim3(64, 4, 4), 256, 0, stream>>>(XtS, XtO, Wb, qb, kvb, psumA,
                                            g1w, g1b, g2w, g2b, Qt8, Kt8, Vv8, gate);
  k_flash8<<<dim3(256, S), 256, 0, stream>>>(Qt8, Kt8, Vv8, localT, gate, Opart16,
                                             Lpart, fusedT);
  k_out<<<dim3(64, 2, 4), 256, 0, stream>>>(Wb + 196608, ob, gate, localT,
                                            S > 1 ? Opart16 : nullptr, Lpart, fusedT,
                                            out, S);
}